// Round 1
// baseline (345.393 us; speedup 1.0000x reference)
//
#include <hip/hip_runtime.h>
#include <math.h>

// Problem constants (fixed by the reference)
#define BG     64      // b*g = 2*32 groups
#define NN     2048    // nodes per group
#define F      128     // IN_F == 2*OUT_F == 128
#define OUTF   64      // OUT_F
#define NSLICE 32      // node slices per group (64 nodes each)
#define SNODES 64      // nodes per slice

// Workspace layout (float offsets)
#define OFF_WEFF 0                                  // [4][128]
#define OFF_CNT  512                                // [BG] int tickets
#define OFF_FP   576                                // [BG*NSLICE][4][128] partial pools
#define OFF_LP   (576 + BG * NSLICE * 4 * F)        // [BG*NSLICE][4] partial exp-sums

// ---------------------------------------------------------------------------
// K1: w_eff[h] = W_h @ a_h. One block per head, fully coalesced float4 W
// reads. Block 0 also zeroes the per-group last-block tickets (the harness
// re-poisons the workspace every iteration, so they must be re-zeroed here;
// kernel-boundary ordering on the stream makes them visible to k_main).
// ---------------------------------------------------------------------------
__global__ __launch_bounds__(256) void k_weff(
    const float* __restrict__ W1, const float* __restrict__ a1,
    const float* __restrict__ W2, const float* __restrict__ a2,
    const float* __restrict__ W3, const float* __restrict__ a3,
    const float* __restrict__ W4, const float* __restrict__ a4,
    float* __restrict__ ws) {
  int h = blockIdx.x, t = threadIdx.x;
  const float* W = (h == 0) ? W1 : (h == 1) ? W2 : (h == 2) ? W3 : W4;
  const float* a = (h == 0) ? a1 : (h == 1) ? a2 : (h == 2) ? a3 : a4;
  __shared__ float aL[F];
  __shared__ float part[F][33];   // +1 pad: conflict-free row sums

  if (h == 0 && t < BG) ((int*)(ws + OFF_CNT))[t] = 0;

  if (t < F) aL[t] = a[t];
  __syncthreads();

  int c = t & 31, r8 = t >> 5;    // chunk, row-octet
#pragma unroll
  for (int it = 0; it < 16; ++it) {
    int row = it * 8 + r8;
    float4 w = ((const float4*)(W + row * F))[c];
    part[row][c] = w.x * aL[4 * c] + w.y * aL[4 * c + 1] +
                   w.z * aL[4 * c + 2] + w.w * aL[4 * c + 3];
  }
  __syncthreads();

  if (t < F) {
    float s = 0.f;
#pragma unroll
    for (int c2 = 0; c2 < 32; ++c2) s += part[t][c2];
    ws[OFF_WEFF + h * F + t] = s;
  }
}

// ---------------------------------------------------------------------------
// K2 (fused): per-slice fused score/exp/pool + per-group finalize.
// Slice phase identical to previous best (XOR chunk swizzle keeps all LDS
// b128 traffic <=2-way). After writing slice partials, each block takes a
// device-scope ticket; the 32nd (last) block of its group runs the
// finalize in-place (decoupled last-block pattern: stores -> threadfence
// -> atomic ticket; last block threadfence -> loads). This removes the
// separate k_final launch + serial tail and overlaps the 64 finalize jobs
// with other groups' pooling work. Finalize GEMVs use coalesced float4
// row-major W/Wo reads + LDS partial reduction (old k_final read W down
// columns at 512-B stride: uncoalesced + latency-bound at 64 blocks).
// Scratch for finalize reuses the dead sfeat buffer, so LDS stays ~40 KB
// -> 4 blocks/CU; launch_bounds(256,4) keeps VGPR <= 128 to protect that.
// ---------------------------------------------------------------------------
__global__ __launch_bounds__(256, 4) void k_main(
    const float* __restrict__ feat,
    const float* __restrict__ W1, const float* __restrict__ W2,
    const float* __restrict__ W3, const float* __restrict__ W4,
    const float* __restrict__ Wo,
    float* __restrict__ ws, float* __restrict__ out) {
  int g = blockIdx.x >> 5;
  int slice = blockIdx.x & (NSLICE - 1);
  int t = threadIdx.x;

  __shared__ float4 sfeat[SNODES * 32];  // row n chunk c at n*32 + (c^(n&31))
  __shared__ float4 weffL[4 * 32];       // w_eff[h] chunk c at h*32 + c
  __shared__ float eLf[SNODES * 4];      // exp(score) [node][head]
  __shared__ float4 pacc[4][2][32];      // [head][half][i4]
  __shared__ float sePf[2][4];           // [half][head] exp-sum partials
  __shared__ int lastFlag;

  if (t < 128) weffL[t] = ((const float4*)(ws + OFF_WEFF))[t];

  // ---- Stage 1: global -> LDS (swizzled), 8 outstanding loads/thread ----
  const float4* fb =
      (const float4*)(feat + ((size_t)g * NN + slice * SNODES) * F);
  float4 ld[8];
#pragma unroll
  for (int k = 0; k < 8; ++k) ld[k] = fb[k * 256 + t];
#pragma unroll
  for (int k = 0; k < 8; ++k) {
    int j = k * 256 + t;
    int n = j >> 5, c = j & 31;
    sfeat[n * 32 + (c ^ (n & 31))] = ld[k];
  }
  __syncthreads();

  // ---- Stage 2: thread (n, h): one head dot + exp ----
  {
    int n = t & 63, h = t >> 6;
    int sw = n & 31, base = n * 32, wb = h * 32;
    float p = 0.f;
#pragma unroll 8
    for (int c = 0; c < 32; ++c) {
      float4 f = sfeat[base + (c ^ sw)];
      float4 w = weffL[wb + c];
      p += f.x * w.x + f.y * w.y + f.z * w.z + f.w * w.w;
    }
    // No max-subtraction: Xavier-bounded scores keep exp() in fp32 range.
    eLf[n * 4 + h] = __expf(p);
  }
  __syncthreads();

  // ---- Stage 3: thread (i4, half, h): pool one head over 32 nodes ----
  {
    int i4 = t & 31, q = (t >> 5) & 1, h = t >> 6;
    float4 a0 = make_float4(0.f, 0.f, 0.f, 0.f);
    float se = 0.f;
#pragma unroll 8
    for (int nn = 0; nn < 32; ++nn) {
      int n = q * 32 + nn;
      float4 f = sfeat[n * 32 + (i4 ^ (n & 31))];
      float e = eLf[n * 4 + h];
      a0.x += e * f.x; a0.y += e * f.y; a0.z += e * f.z; a0.w += e * f.w;
      se += e;
    }
    pacc[h][q][i4] = a0;
    if (i4 == 0) sePf[q][h] = se;
  }
  __syncthreads();

  // ---- Combine halves, write slice partials to ws ----
  if (t < 128) {
    int i4 = t & 31, h = t >> 5;
    float4 s0 = pacc[h][0][i4], s1 = pacc[h][1][i4];
    float4 s = make_float4(s0.x + s1.x, s0.y + s1.y,
                           s0.z + s1.z, s0.w + s1.w);
    ((float4*)(ws + OFF_FP))[(size_t)(g * NSLICE + slice) * 128 + h * 32 + i4] = s;
  }
  if (t == 0) {
    float4 L = make_float4(sePf[0][0] + sePf[1][0], sePf[0][1] + sePf[1][1],
                           sePf[0][2] + sePf[1][2], sePf[0][3] + sePf[1][3]);
    ((float4*)(ws + OFF_LP))[g * NSLICE + slice] = L;
  }

  // ---- Release our partials, take a ticket; last block of group finishes --
  __threadfence();                 // release: partials visible device-wide
  __syncthreads();
  if (t == 0) {
    int old = atomicAdd((int*)(ws + OFF_CNT) + g, 1);
    lastFlag = (old == NSLICE - 1) ? 1 : 0;
  }
  __syncthreads();
  if (!lastFlag) return;
  __threadfence();                 // acquire: see all slices' partials

  // ======================= per-group finalize ============================
  // Scratch overlay on sfeat (32 KB; finalize needs < 16 KB):
  //   f4[0..255]    : pooled half-sums (2 x 128 float4)  -> later Wo partials
  //   f4[256..383]  : normalized fp (4 heads x 128 floats)
  //   f4[512..767]  : W-GEMV partials (8 x 32 float4)
  //   f4[768..895]  : multi (512 floats)
  //   fbuf[8188..]  : invl[4]
  float* fbuf = (float*)sfeat;
  float4* f4 = (float4*)sfeat;
  const float4* FP4 = (const float4*)(ws + OFF_FP) + (size_t)g * NSLICE * 128;

  if (t < 4) {
    float s = 0.f;
#pragma unroll
    for (int sl = 0; sl < NSLICE; ++sl)
      s += ws[OFF_LP + (g * NSLICE + sl) * 4 + t];
    fbuf[8188 + t] = 1.0f / s;
  }
  {
    int j = t & 127, half = t >> 7;
    float4 s4 = make_float4(0.f, 0.f, 0.f, 0.f);
#pragma unroll
    for (int sl = 0; sl < 16; ++sl) {
      float4 v = FP4[(half * 16 + sl) * 128 + j];
      s4.x += v.x; s4.y += v.y; s4.z += v.z; s4.w += v.w;
    }
    f4[half * 128 + j] = s4;
  }
  __syncthreads();
  if (t < 128) {
    float4 a = f4[t], b = f4[128 + t];
    float inv = fbuf[8188 + (t >> 5)];
    f4[256 + t] = make_float4((a.x + b.x) * inv, (a.y + b.y) * inv,
                              (a.z + b.z) * inv, (a.w + b.w) * inv);
  }
  __syncthreads();

  // multi[h*128+col] = fp_h . W_h[:,col] — coalesced float4 rows of W_h,
  // 2 row-groups of 64 per head, LDS partial combine.
  {
    int c = t & 31, rg = (t >> 5) & 1, h = t >> 6;
    const float* Wsel = (h == 0) ? W1 : (h == 1) ? W2 : (h == 2) ? W3 : W4;
    const float4* W4p = (const float4*)Wsel;
    const float* fph = fbuf + 1024 + h * F;
    float4 acc = make_float4(0.f, 0.f, 0.f, 0.f);
#pragma unroll 8
    for (int k = 0; k < 64; ++k) {
      int i = rg * 64 + k;
      float s = fph[i];
      float4 w = W4p[i * 32 + c];
      acc.x += s * w.x; acc.y += s * w.y; acc.z += s * w.z; acc.w += s * w.w;
    }
    f4[512 + (h * 2 + rg) * 32 + c] = acc;
  }
  __syncthreads();
  if (t < 128) {
    int h = t >> 5, c = t & 31;
    float4 a = f4[512 + (h * 2) * 32 + c];
    float4 b = f4[512 + (h * 2 + 1) * 32 + c];
    f4[768 + h * 32 + c] = make_float4(a.x + b.x, a.y + b.y,
                                       a.z + b.z, a.w + b.w);
  }
  __syncthreads();

  // out[o] = elu(multi . Wo[:,o]) — coalesced float4 rows of Wo,
  // 16 row-groups of 32, LDS partial combine (reuses f4[0..255]).
  {
    int o4 = t & 15, rg = t >> 4;
    const float4* Wo4 = (const float4*)Wo;
    const float* mu = fbuf + 3072;
    float4 acc = make_float4(0.f, 0.f, 0.f, 0.f);
#pragma unroll 8
    for (int k = 0; k < 32; ++k) {
      int i = rg * 32 + k;
      float s = mu[i];
      float4 w = Wo4[i * 16 + o4];
      acc.x += s * w.x; acc.y += s * w.y; acc.z += s * w.z; acc.w += s * w.w;
    }
    f4[rg * 16 + o4] = acc;
  }
  __syncthreads();
  if (t < OUTF) {
    float s = 0.f;
#pragma unroll
    for (int rg = 0; rg < 16; ++rg) s += fbuf[rg * 64 + t];
    out[g * OUTF + t] = (s > 0.f) ? s : expm1f(s);
  }
}

// ---------------------------------------------------------------------------
extern "C" void kernel_launch(void* const* d_in, const int* in_sizes, int n_in,
                              void* d_out, int out_size, void* d_ws, size_t ws_size,
                              hipStream_t stream) {
  const float* feat = (const float*)d_in[0];
  const float* W1 = (const float*)d_in[1];
  const float* a1 = (const float*)d_in[2];
  const float* W2 = (const float*)d_in[3];
  const float* a2 = (const float*)d_in[4];
  const float* W3 = (const float*)d_in[5];
  const float* a3 = (const float*)d_in[6];
  const float* W4 = (const float*)d_in[7];
  const float* a4 = (const float*)d_in[8];
  const float* Wo = (const float*)d_in[9];
  float* ws = (float*)d_ws;
  float* out = (float*)d_out;

  k_weff<<<4, 256, 0, stream>>>(W1, a1, W2, a2, W3, a3, W4, a4, ws);
  k_main<<<BG * NSLICE, 256, 0, stream>>>(feat, W1, W2, W3, W4, Wo, ws, out);
}

// Round 2
// 123.473 us; speedup vs baseline: 2.7973x; 2.7973x over previous
//
#include <hip/hip_runtime.h>
#include <math.h>

// Problem constants (fixed by the reference)
#define BG     64      // b*g = 2*32 groups
#define NN     2048    // nodes per group
#define F      128     // IN_F == 2*OUT_F == 128
#define OUTF   64      // OUT_F
#define NSLICE 32      // node slices per group (64 nodes each)
#define SNODES 64      // nodes per slice

// Workspace layout (float offsets)
#define OFF_WEFF 0                                  // [4][128]
#define OFF_FP   512                                // [BG*NSLICE][4][128] partial pools
#define OFF_LP   (512 + BG * NSLICE * 4 * F)        // [BG*NSLICE][4] partial exp-sums

// ---------------------------------------------------------------------------
// K1: w_eff[h] = W_h @ a_h. One block per head, fully coalesced float4 W
// reads (row-per-thread W reads are 16x line-amplified).
// score_n = (feat_n @ W) . a = feat_n . (W @ a); pooled = (sum p_n feat_n) @ W
// ---------------------------------------------------------------------------
__global__ __launch_bounds__(256) void k_weff(
    const float* __restrict__ W1, const float* __restrict__ a1,
    const float* __restrict__ W2, const float* __restrict__ a2,
    const float* __restrict__ W3, const float* __restrict__ a3,
    const float* __restrict__ W4, const float* __restrict__ a4,
    float* __restrict__ ws) {
  int h = blockIdx.x, t = threadIdx.x;
  const float* W = (h == 0) ? W1 : (h == 1) ? W2 : (h == 2) ? W3 : W4;
  const float* a = (h == 0) ? a1 : (h == 1) ? a2 : (h == 2) ? a3 : a4;
  __shared__ float aL[F];
  __shared__ float part[F][33];   // +1 pad: conflict-free row sums

  if (t < F) aL[t] = a[t];
  __syncthreads();

  int c = t & 31, r8 = t >> 5;    // chunk, row-octet
#pragma unroll
  for (int it = 0; it < 16; ++it) {
    int row = it * 8 + r8;
    float4 w = ((const float4*)(W + row * F))[c];
    part[row][c] = w.x * aL[4 * c] + w.y * aL[4 * c + 1] +
                   w.z * aL[4 * c + 2] + w.w * aL[4 * c + 3];
  }
  __syncthreads();

  if (t < F) {
    float s = 0.f;
#pragma unroll
    for (int c2 = 0; c2 < 32; ++c2) s += part[t][c2];
    ws[OFF_WEFF + h * F + t] = s;
  }
}

// ---------------------------------------------------------------------------
// K2: per-slice fused score/exp/pool, 64-node slices, ~40 KB LDS ->
// 4 blocks/CU. XOR chunk swizzle (c ^ (n&31)) keeps all LDS b128 traffic
// <=2-way (free on CDNA4).
// R1 lesson: NO device-fence fusion here — __threadfence() per block is an
// agent-scope L2 writeback on gfx950; 2048 of them cost ~230 µs. The
// kernel boundary below is the free, one-time device fence.
// ---------------------------------------------------------------------------
__global__ __launch_bounds__(256) void k_main(
    const float* __restrict__ feat, float* __restrict__ ws) {
  int g = blockIdx.x >> 5;
  int slice = blockIdx.x & (NSLICE - 1);
  int t = threadIdx.x;

  __shared__ float4 sfeat[SNODES * 32];  // row n chunk c at n*32 + (c^(n&31))
  __shared__ float4 weffL[4 * 32];       // w_eff[h] chunk c at h*32 + c
  __shared__ float eLf[SNODES * 4];      // exp(score) [node][head]
  __shared__ float4 pacc[4][2][32];      // [head][half][i4]
  __shared__ float sePf[2][4];           // [half][head] exp-sum partials

  if (t < 128) weffL[t] = ((const float4*)(ws + OFF_WEFF))[t];

  // ---- Stage 1: global -> LDS (swizzled), 8 outstanding loads/thread ----
  const float4* fb =
      (const float4*)(feat + ((size_t)g * NN + slice * SNODES) * F);
  float4 ld[8];
#pragma unroll
  for (int k = 0; k < 8; ++k) ld[k] = fb[k * 256 + t];
#pragma unroll
  for (int k = 0; k < 8; ++k) {
    int j = k * 256 + t;
    int n = j >> 5, c = j & 31;
    sfeat[n * 32 + (c ^ (n & 31))] = ld[k];
  }
  __syncthreads();

  // ---- Stage 2: thread (n, h): one head dot + exp ----
  {
    int n = t & 63, h = t >> 6;
    int sw = n & 31, base = n * 32, wb = h * 32;
    float p = 0.f;
#pragma unroll 8
    for (int c = 0; c < 32; ++c) {
      float4 f = sfeat[base + (c ^ sw)];
      float4 w = weffL[wb + c];
      p += f.x * w.x + f.y * w.y + f.z * w.z + f.w * w.w;
    }
    // No max-subtraction: Xavier-bounded scores keep exp() in fp32 range.
    eLf[n * 4 + h] = __expf(p);
  }
  __syncthreads();

  // ---- Stage 3: thread (i4, half, h): pool one head over 32 nodes ----
  {
    int i4 = t & 31, q = (t >> 5) & 1, h = t >> 6;
    float4 a0 = make_float4(0.f, 0.f, 0.f, 0.f);
    float se = 0.f;
#pragma unroll 8
    for (int nn = 0; nn < 32; ++nn) {
      int n = q * 32 + nn;
      float4 f = sfeat[n * 32 + (i4 ^ (n & 31))];
      float e = eLf[n * 4 + h];
      a0.x += e * f.x; a0.y += e * f.y; a0.z += e * f.z; a0.w += e * f.w;
      se += e;
    }
    pacc[h][q][i4] = a0;
    if (i4 == 0) sePf[q][h] = se;
  }
  __syncthreads();

  // ---- Combine halves, write slice partials to ws ----
  if (t < 128) {
    int i4 = t & 31, h = t >> 5;
    float4 s0 = pacc[h][0][i4], s1 = pacc[h][1][i4];
    float4 s = make_float4(s0.x + s1.x, s0.y + s1.y,
                           s0.z + s1.z, s0.w + s1.w);
    ((float4*)(ws + OFF_FP))[(size_t)(g * NSLICE + slice) * 128 + h * 32 + i4] = s;
  }
  if (t == 0) {
    float4 L = make_float4(sePf[0][0] + sePf[1][0], sePf[0][1] + sePf[1][1],
                           sePf[0][2] + sePf[1][2], sePf[0][3] + sePf[1][3]);
    ((float4*)(ws + OFF_LP))[g * NSLICE + slice] = L;
  }
}

// ---------------------------------------------------------------------------
// K3: combine slice partials, normalize, pooled@W_h, concat@Wo, ELU.
// One block (256 threads) per group. Rewritten vs round-0: both GEMVs read
// W_h / Wo as coalesced float4 ROWS with LDS partial reduction (the old
// version walked W columns at 512-B stride per thread: 16x line
// amplification, latency-bound at 2 waves/CU).
// ---------------------------------------------------------------------------
__global__ __launch_bounds__(256) void k_final(
    const float* __restrict__ W1, const float* __restrict__ W2,
    const float* __restrict__ W3, const float* __restrict__ W4,
    const float* __restrict__ Wo, const float* __restrict__ ws,
    float* __restrict__ out) {
  int g = blockIdx.x;
  int t = threadIdx.x;  // 0..255

  // Scratch layout (float4 indices):
  //   f4[0..255]   : pooled half-sums (2 x 128)  -> later Wo GEMV partials
  //   f4[256..383] : normalized fp (4 heads x 128 floats)
  //   f4[512..767] : W-GEMV partials (8 x 32)
  //   f4[768..895] : multi (512 floats)
  __shared__ float4 f4[896];
  __shared__ float invl[4];
  float* fbuf = (float*)f4;

  const float4* FP4 = (const float4*)(ws + OFF_FP) + (size_t)g * NSLICE * 128;

  if (t < 4) {
    float s = 0.f;
#pragma unroll
    for (int sl = 0; sl < NSLICE; ++sl)
      s += ws[OFF_LP + (g * NSLICE + sl) * 4 + t];
    invl[t] = 1.0f / s;
  }
  // Pooled half-sums: thread (j, half) sums 16 slices of element j.
  {
    int j = t & 127, half = t >> 7;
    float4 s4 = make_float4(0.f, 0.f, 0.f, 0.f);
#pragma unroll
    for (int sl = 0; sl < 16; ++sl) {
      float4 v = FP4[(size_t)(half * 16 + sl) * 128 + j];
      s4.x += v.x; s4.y += v.y; s4.z += v.z; s4.w += v.w;
    }
    f4[half * 128 + j] = s4;
  }
  __syncthreads();
  if (t < 128) {
    float4 a = f4[t], b = f4[128 + t];
    float inv = invl[t >> 5];
    f4[256 + t] = make_float4((a.x + b.x) * inv, (a.y + b.y) * inv,
                              (a.z + b.z) * inv, (a.w + b.w) * inv);
  }
  __syncthreads();

  // multi[h*128+col] = fp_h . W_h[:,col] — coalesced float4 rows of W_h,
  // 2 row-groups of 64 per head, LDS partial combine.
  {
    int c = t & 31, rg = (t >> 5) & 1, h = t >> 6;
    const float* Wsel = (h == 0) ? W1 : (h == 1) ? W2 : (h == 2) ? W3 : W4;
    const float4* W4p = (const float4*)Wsel;
    const float* fph = fbuf + 1024 + h * F;  // = f4[256 + h*32 ...]
    float4 acc = make_float4(0.f, 0.f, 0.f, 0.f);
#pragma unroll 8
    for (int k = 0; k < 64; ++k) {
      int i = rg * 64 + k;
      float s = fph[i];
      float4 w = W4p[i * 32 + c];
      acc.x += s * w.x; acc.y += s * w.y; acc.z += s * w.z; acc.w += s * w.w;
    }
    f4[512 + (h * 2 + rg) * 32 + c] = acc;
  }
  __syncthreads();
  if (t < 128) {
    int h = t >> 5, c = t & 31;
    float4 a = f4[512 + (h * 2) * 32 + c];
    float4 b = f4[512 + (h * 2 + 1) * 32 + c];
    f4[768 + h * 32 + c] = make_float4(a.x + b.x, a.y + b.y,
                                       a.z + b.z, a.w + b.w);
  }
  __syncthreads();

  // out[o] = elu(multi . Wo[:,o]) — coalesced float4 rows of Wo,
  // 16 row-groups of 32, LDS partial combine (reuses f4[0..255]).
  {
    int o4 = t & 15, rg = t >> 4;
    const float4* Wo4 = (const float4*)Wo;
    const float* mu = fbuf + 3072;  // = f4[768..]
    float4 acc = make_float4(0.f, 0.f, 0.f, 0.f);
#pragma unroll 8
    for (int k = 0; k < 32; ++k) {
      int i = rg * 32 + k;
      float s = mu[i];
      float4 w = Wo4[i * 16 + o4];
      acc.x += s * w.x; acc.y += s * w.y; acc.z += s * w.z; acc.w += s * w.w;
    }
    f4[rg * 16 + o4] = acc;
  }
  __syncthreads();
  if (t < OUTF) {
    float s = 0.f;
#pragma unroll
    for (int rg = 0; rg < 16; ++rg) s += fbuf[rg * 64 + t];
    out[g * OUTF + t] = (s > 0.f) ? s : expm1f(s);
  }
}

// ---------------------------------------------------------------------------
extern "C" void kernel_launch(void* const* d_in, const int* in_sizes, int n_in,
                              void* d_out, int out_size, void* d_ws, size_t ws_size,
                              hipStream_t stream) {
  const float* feat = (const float*)d_in[0];
  const float* W1 = (const float*)d_in[1];
  const float* a1 = (const float*)d_in[2];
  const float* W2 = (const float*)d_in[3];
  const float* a2 = (const float*)d_in[4];
  const float* W3 = (const float*)d_in[5];
  const float* a3 = (const float*)d_in[6];
  const float* W4 = (const float*)d_in[7];
  const float* a4 = (const float*)d_in[8];
  const float* Wo = (const float*)d_in[9];
  float* ws = (float*)d_ws;
  float* out = (float*)d_out;

  k_weff<<<4, 256, 0, stream>>>(W1, a1, W2, a2, W3, a3, W4, a4, ws);
  k_main<<<BG * NSLICE, 256, 0, stream>>>(feat, ws);
  k_final<<<BG, 256, 0, stream>>>(W1, W2, W3, W4, Wo, ws, out);
}

// Round 3
// 121.471 us; speedup vs baseline: 2.8434x; 1.0165x over previous
//
#include <hip/hip_runtime.h>
#include <math.h>

// Problem constants (fixed by the reference)
#define BG     64      // b*g = 2*32 groups
#define NN     2048    // nodes per group
#define F      128     // IN_F == 2*OUT_F == 128
#define OUTF   64      // OUT_F
#define NSLICE 64      // node slices per group (32 nodes each)
#define SNODES 32      // nodes per slice

// Workspace layout (float offsets)
#define OFF_WEFF 0                                  // [4][128]
#define OFF_FP   512                                // [BG*NSLICE][4][128] partial pools
#define OFF_LP   (512 + BG * NSLICE * 4 * F)        // [BG*NSLICE][4] partial exp-sums

// ---------------------------------------------------------------------------
// K1: w_eff[h] = W_h @ a_h. One block per head, fully coalesced float4 W
// reads. score_n = (feat_n @ W) . a = feat_n . (W @ a).
// ---------------------------------------------------------------------------
__global__ __launch_bounds__(256) void k_weff(
    const float* __restrict__ W1, const float* __restrict__ a1,
    const float* __restrict__ W2, const float* __restrict__ a2,
    const float* __restrict__ W3, const float* __restrict__ a3,
    const float* __restrict__ W4, const float* __restrict__ a4,
    float* __restrict__ ws) {
  int h = blockIdx.x, t = threadIdx.x;
  const float* W = (h == 0) ? W1 : (h == 1) ? W2 : (h == 2) ? W3 : W4;
  const float* a = (h == 0) ? a1 : (h == 1) ? a2 : (h == 2) ? a3 : a4;
  __shared__ float aL[F];
  __shared__ float part[F][33];   // +1 pad: conflict-free row sums

  if (t < F) aL[t] = a[t];
  __syncthreads();

  int c = t & 31, r8 = t >> 5;    // chunk, row-octet
#pragma unroll
  for (int it = 0; it < 16; ++it) {
    int row = it * 8 + r8;
    float4 w = ((const float4*)(W + row * F))[c];
    part[row][c] = w.x * aL[4 * c] + w.y * aL[4 * c + 1] +
                   w.z * aL[4 * c + 2] + w.w * aL[4 * c + 3];
  }
  __syncthreads();

  if (t < F) {
    float s = 0.f;
#pragma unroll
    for (int c2 = 0; c2 < 32; ++c2) s += part[t][c2];
    ws[OFF_WEFF + h * F + t] = s;
  }
}

// ---------------------------------------------------------------------------
// K2: per-slice fused score/exp/pool. R3 change: 32-node slices, LDS
// ~22.6 KB -> 7 blocks/CU (was 40.4 KB -> 3-4 blocks/CU, OccupancyPercent
// 27%). Theory: k_main was residency/latency-bound at ~2 TB/s effective;
// 7 resident blocks/CU lets load phases of some blocks cover barrier-
// serialized compute of others. XOR chunk swizzle (c ^ n) keeps LDS b128
// traffic patterns identical to the proven 64-node version.
// R1 lesson kept: NO __threadfence fusion (agent-scope L2 writeback).
// ---------------------------------------------------------------------------
__global__ __launch_bounds__(256) void k_main(
    const float* __restrict__ feat, float* __restrict__ ws) {
  int g = blockIdx.x >> 6;
  int slice = blockIdx.x & (NSLICE - 1);
  int t = threadIdx.x;

  __shared__ float4 sfeat[SNODES * 32];  // row n chunk c at n*32 + (c^n)
  __shared__ float4 weffL[4 * 32];       // w_eff[h] chunk c at h*32 + c
  __shared__ float eLf[SNODES * 4];      // exp(score) [node][head]
  __shared__ float4 pacc[4][2][32];      // [head][half][i4]
  __shared__ float sePf[2][4];           // [half][head] exp-sum partials

  if (t < 128) weffL[t] = ((const float4*)(ws + OFF_WEFF))[t];

  // ---- Stage 1: global -> LDS (swizzled), 4 outstanding loads/thread ----
  const float4* fb =
      (const float4*)(feat + ((size_t)g * NN + slice * SNODES) * F);
  float4 ld[4];
#pragma unroll
  for (int k = 0; k < 4; ++k) ld[k] = fb[k * 256 + t];
#pragma unroll
  for (int k = 0; k < 4; ++k) {
    int j = k * 256 + t;
    int n = j >> 5, c = j & 31;
    sfeat[n * 32 + (c ^ n)] = ld[k];
  }
  __syncthreads();

  // ---- Stage 2: threads 0..127 = (n, h): one head dot + exp ----
  if (t < 128) {
    int n = t & 31, h = t >> 5;
    int base = n * 32, wb = h * 32;
    float p = 0.f;
#pragma unroll 8
    for (int c = 0; c < 32; ++c) {
      float4 f = sfeat[base + (c ^ n)];
      float4 w = weffL[wb + c];
      p += f.x * w.x + f.y * w.y + f.z * w.z + f.w * w.w;
    }
    // No max-subtraction: Xavier-bounded scores keep exp() in fp32 range.
    eLf[n * 4 + h] = __expf(p);
  }
  __syncthreads();

  // ---- Stage 3: thread (i4, half, h): pool one head over 16 nodes ----
  {
    int i4 = t & 31, q = (t >> 5) & 1, h = t >> 6;
    float4 a0 = make_float4(0.f, 0.f, 0.f, 0.f);
    float se = 0.f;
#pragma unroll 8
    for (int nn = 0; nn < 16; ++nn) {
      int n = q * 16 + nn;
      float4 f = sfeat[n * 32 + (i4 ^ n)];
      float e = eLf[n * 4 + h];
      a0.x += e * f.x; a0.y += e * f.y; a0.z += e * f.z; a0.w += e * f.w;
      se += e;
    }
    pacc[h][q][i4] = a0;
    if (i4 == 0) sePf[q][h] = se;
  }
  __syncthreads();

  // ---- Combine halves, write slice partials to ws ----
  if (t < 128) {
    int i4 = t & 31, h = t >> 5;
    float4 s0 = pacc[h][0][i4], s1 = pacc[h][1][i4];
    float4 s = make_float4(s0.x + s1.x, s0.y + s1.y,
                           s0.z + s1.z, s0.w + s1.w);
    ((float4*)(ws + OFF_FP))[(size_t)(g * NSLICE + slice) * 128 + h * 32 + i4] = s;
  }
  if (t == 0) {
    float4 L = make_float4(sePf[0][0] + sePf[1][0], sePf[0][1] + sePf[1][1],
                           sePf[0][2] + sePf[1][2], sePf[0][3] + sePf[1][3]);
    ((float4*)(ws + OFF_LP))[g * NSLICE + slice] = L;
  }
}

// ---------------------------------------------------------------------------
// K3: combine slice partials, normalize, pooled@W_h, concat@Wo, ELU.
// One block (256 threads) per group; coalesced float4 rows + LDS combine.
// ---------------------------------------------------------------------------
__global__ __launch_bounds__(256) void k_final(
    const float* __restrict__ W1, const float* __restrict__ W2,
    const float* __restrict__ W3, const float* __restrict__ W4,
    const float* __restrict__ Wo, const float* __restrict__ ws,
    float* __restrict__ out) {
  int g = blockIdx.x;
  int t = threadIdx.x;  // 0..255

  // Scratch layout (float4 indices):
  //   f4[0..255]   : pooled half-sums (2 x 128)  -> later Wo GEMV partials
  //   f4[256..383] : normalized fp (4 heads x 128 floats)
  //   f4[512..767] : W-GEMV partials (8 x 32)
  //   f4[768..895] : multi (512 floats)
  __shared__ float4 f4[896];
  __shared__ float invl[4];
  float* fbuf = (float*)f4;

  const float4* FP4 = (const float4*)(ws + OFF_FP) + (size_t)g * NSLICE * 128;

  if (t < 4) {
    float s = 0.f;
#pragma unroll
    for (int sl = 0; sl < NSLICE; ++sl)
      s += ws[OFF_LP + (g * NSLICE + sl) * 4 + t];
    invl[t] = 1.0f / s;
  }
  // Pooled half-sums: thread (j, half) sums 32 slices of element j.
  {
    int j = t & 127, half = t >> 7;
    float4 s4 = make_float4(0.f, 0.f, 0.f, 0.f);
#pragma unroll
    for (int sl = 0; sl < 32; ++sl) {
      float4 v = FP4[(size_t)(half * 32 + sl) * 128 + j];
      s4.x += v.x; s4.y += v.y; s4.z += v.z; s4.w += v.w;
    }
    f4[half * 128 + j] = s4;
  }
  __syncthreads();
  if (t < 128) {
    float4 a = f4[t], b = f4[128 + t];
    float inv = invl[t >> 5];
    f4[256 + t] = make_float4((a.x + b.x) * inv, (a.y + b.y) * inv,
                              (a.z + b.z) * inv, (a.w + b.w) * inv);
  }
  __syncthreads();

  // multi[h*128+col] = fp_h . W_h[:,col] — coalesced float4 rows of W_h,
  // 2 row-groups of 64 per head, LDS partial combine.
  {
    int c = t & 31, rg = (t >> 5) & 1, h = t >> 6;
    const float* Wsel = (h == 0) ? W1 : (h == 1) ? W2 : (h == 2) ? W3 : W4;
    const float4* W4p = (const float4*)Wsel;
    const float* fph = fbuf + 1024 + h * F;  // = f4[256 + h*32 ...]
    float4 acc = make_float4(0.f, 0.f, 0.f, 0.f);
#pragma unroll 8
    for (int k = 0; k < 64; ++k) {
      int i = rg * 64 + k;
      float s = fph[i];
      float4 w = W4p[i * 32 + c];
      acc.x += s * w.x; acc.y += s * w.y; acc.z += s * w.z; acc.w += s * w.w;
    }
    f4[512 + (h * 2 + rg) * 32 + c] = acc;
  }
  __syncthreads();
  if (t < 128) {
    int h = t >> 5, c = t & 31;
    float4 a = f4[512 + (h * 2) * 32 + c];
    float4 b = f4[512 + (h * 2 + 1) * 32 + c];
    f4[768 + h * 32 + c] = make_float4(a.x + b.x, a.y + b.y,
                                       a.z + b.z, a.w + b.w);
  }
  __syncthreads();

  // out[o] = elu(multi . Wo[:,o]) — coalesced float4 rows of Wo,
  // 16 row-groups of 32, LDS partial combine (reuses f4[0..255]).
  {
    int o4 = t & 15, rg = t >> 4;
    const float4* Wo4 = (const float4*)Wo;
    const float* mu = fbuf + 3072;  // = f4[768..]
    float4 acc = make_float4(0.f, 0.f, 0.f, 0.f);
#pragma unroll 8
    for (int k = 0; k < 32; ++k) {
      int i = rg * 32 + k;
      float s = mu[i];
      float4 w = Wo4[i * 16 + o4];
      acc.x += s * w.x; acc.y += s * w.y; acc.z += s * w.z; acc.w += s * w.w;
    }
    f4[rg * 16 + o4] = acc;
  }
  __syncthreads();
  if (t < OUTF) {
    float s = 0.f;
#pragma unroll
    for (int rg = 0; rg < 16; ++rg) s += fbuf[rg * 64 + t];
    out[g * OUTF + t] = (s > 0.f) ? s : expm1f(s);
  }
}

// ---------------------------------------------------------------------------
extern "C" void kernel_launch(void* const* d_in, const int* in_sizes, int n_in,
                              void* d_out, int out_size, void* d_ws, size_t ws_size,
                              hipStream_t stream) {
  const float* feat = (const float*)d_in[0];
  const float* W1 = (const float*)d_in[1];
  const float* a1 = (const float*)d_in[2];
  const float* W2 = (const float*)d_in[3];
  const float* a2 = (const float*)d_in[4];
  const float* W3 = (const float*)d_in[5];
  const float* a3 = (const float*)d_in[6];
  const float* W4 = (const float*)d_in[7];
  const float* a4 = (const float*)d_in[8];
  const float* Wo = (const float*)d_in[9];
  float* ws = (float*)d_ws;
  float* out = (float*)d_out;

  k_weff<<<4, 256, 0, stream>>>(W1, a1, W2, a2, W3, a3, W4, a4, ws);
  k_main<<<BG * NSLICE, 256, 0, stream>>>(feat, ws);
  k_final<<<BG, 256, 0, stream>>>(W1, W2, W3, W4, Wo, ws, out);
}